// Round 1
// baseline (680.510 us; speedup 1.0000x reference)
//
#include <hip/hip_runtime.h>

// Problem constants (fixed by reference): B=32, H=W=64, C=384, ws=8, heads=12, hd=32
// windows = 32 * 8*8 = 2048, tokens/window N=64.

typedef __attribute__((ext_vector_type(8))) short bf16x8;   // 8 bf16 = 4 VGPRs (MFMA A/B frag)
typedef __attribute__((ext_vector_type(4))) float f32x4;    // MFMA C/D frag
typedef __attribute__((ext_vector_type(4))) short short4_t;

__device__ __forceinline__ short f2bf(float f) {
    union { float f; unsigned u; } v; v.f = f;
    unsigned r = v.u + 0x7fffu + ((v.u >> 16) & 1u);   // RNE
    return (short)(r >> 16);
}

__device__ __forceinline__ f32x4 mfma16(bf16x8 a, bf16x8 b, f32x4 c) {
    return __builtin_amdgcn_mfma_f32_16x16x32_bf16(a, b, c, 0, 0, 0);
}

// ---- kernel 0: fp32 weights -> bf16, transposed to [n][k] so B-frags read contiguous K ----
__global__ void prep_weights(const float* __restrict__ wqkv, const float* __restrict__ wproj,
                             short* __restrict__ wq_t, short* __restrict__ wp_t) {
    int i = blockIdx.x * 256 + threadIdx.x;
    if (i < 1152 * 384) {
        int n = i / 384, k = i % 384;
        wq_t[i] = f2bf(wqkv[k * 1152 + n]);
    } else if (i < 1152 * 384 + 384 * 384) {
        int j = i - 1152 * 384;
        int n = j / 384, k = j % 384;
        wp_t[j] = f2bf(wproj[k * 384 + n]);
    }
}

// ---- fused window attention: QKV GEMM + softmax(QK^T)V + proj, one block per window ----
__global__ __launch_bounds__(256, 2)
void win_attn(const float* __restrict__ x, const short* __restrict__ wq_t,
              const short* __restrict__ wp_t, const float* __restrict__ b_proj,
              float* __restrict__ out) {
    __shared__ short xs[64 * 392];   // x window, bf16, padded stride (2-way banks) 50176 B
    __shared__ short q_s[64 * 40];   // Q [token][dim], pre-scaled                   5120 B
    __shared__ short k_s[64 * 40];   // K [token][dim]                               5120 B
    __shared__ short v_t[32 * 72];   // V^T [dim][token] (B-frag wants K-contig)     4608 B
    __shared__ short ps[64 * 72];    // P [row][col]; reused as y_head [tok][dim]    9216 B
    // total 74,240 B -> 2 blocks/CU

    const int tid   = threadIdx.x;
    const int lane  = tid & 63;
    const int wv    = tid >> 6;       // wave 0..3
    const int col16 = lane & 15;
    const int kgrp  = lane >> 4;      // 0..3
    const int wm    = wv >> 1;        // M-half for GEMM phases
    const int wn    = wv & 1;         // N-half

    const int win = blockIdx.x;
    const int b   = win >> 6, wi = win & 63, whr = wi >> 3, wwc = wi & 7;
    const float* xbase = x + (((b * 64) + whr * 8) * 64 + wwc * 8) * 384;

    // ---- stage x -> LDS as bf16 (window rows are 8x contiguous 3072-float runs) ----
    for (int i = tid; i < 64 * 96; i += 256) {
        int t = i / 96, c4 = (i % 96) * 4;
        float4 v = *reinterpret_cast<const float4*>(xbase + ((t >> 3) * 64 + (t & 7)) * 384 + c4);
        short4_t s;
        s.x = f2bf(v.x); s.y = f2bf(v.y); s.z = f2bf(v.z); s.w = f2bf(v.w);
        *reinterpret_cast<short4_t*>(&xs[t * 392 + c4]) = s;
    }
    __syncthreads();

    const float scale = 0.17677669529663687f;   // 32^-0.5, folded into Q

    // proj accumulators, updated rank-32 per head (stays in regs: 96 VGPR)
    f32x4 pacc[2][12];
#pragma unroll
    for (int i = 0; i < 2; ++i)
#pragma unroll
        for (int j = 0; j < 12; ++j) pacc[i][j] = (f32x4){0.f, 0.f, 0.f, 0.f};

    for (int h = 0; h < 12; ++h) {
        // ---- QKV GEMM: xs[64x384] @ Wh[384x96]; waves 2x2 over (2M x 3N) 16x16 tiles ----
        f32x4 acc[2][3];
#pragma unroll
        for (int i = 0; i < 2; ++i)
#pragma unroll
            for (int j = 0; j < 3; ++j) acc[i][j] = (f32x4){0.f, 0.f, 0.f, 0.f};

        const short* bptr[3];
#pragma unroll
        for (int jj = 0; jj < 3; ++jj) {
            int j = wn * 3 + jj;               // global N-tile 0..5 = q0 q1 k0 k1 v0 v1
            int sec = j >> 1;                  // 0=q,1=k,2=v section of w_qkv columns
            int nrow = sec * 384 + h * 32 + (j & 1) * 16 + col16;
            bptr[jj] = wq_t + nrow * 384;
        }
#pragma unroll
        for (int kk = 0; kk < 12; ++kk) {
            const int kb = kk * 32 + kgrp * 8;
            bf16x8 a0 = *reinterpret_cast<const bf16x8*>(&xs[(wm * 32 + col16) * 392 + kb]);
            bf16x8 a1 = *reinterpret_cast<const bf16x8*>(&xs[(wm * 32 + 16 + col16) * 392 + kb]);
#pragma unroll
            for (int jj = 0; jj < 3; ++jj) {
                bf16x8 bb = *reinterpret_cast<const bf16x8*>(&bptr[jj][kb]);
                acc[0][jj] = mfma16(a0, bb, acc[0][jj]);
                acc[1][jj] = mfma16(a1, bb, acc[1][jj]);
            }
        }
        // scatter to q_s/k_s/v_t (C-layout: col=lane&15, row=kgrp*4+r)
#pragma unroll
        for (int mt = 0; mt < 2; ++mt) {
#pragma unroll
            for (int jj = 0; jj < 3; ++jj) {
                int j = wn * 3 + jj;
#pragma unroll
                for (int r = 0; r < 4; ++r) {
                    int token = (wm * 2 + mt) * 16 + kgrp * 4 + r;
                    float val = acc[mt][jj][r];
                    if (j < 2)       q_s[token * 40 + (j & 1) * 16 + col16] = f2bf(val * scale);
                    else if (j < 4)  k_s[token * 40 + ((j - 2) & 1) * 16 + col16] = f2bf(val);
                    else             v_t[((j - 4) * 16 + col16) * 72 + token] = f2bf(val);
                }
            }
        }
        __syncthreads();   // SYNC1: qkv visible to all waves

        // ---- scores: wave w owns M-tile w (rows w*16..+15) x all 4 N-tiles ----
        bf16x8 qa = *reinterpret_cast<const bf16x8*>(&q_s[(wv * 16 + col16) * 40 + kgrp * 8]);
        f32x4 sc[4];
#pragma unroll
        for (int nt = 0; nt < 4; ++nt) {
            bf16x8 kf = *reinterpret_cast<const bf16x8*>(&k_s[(nt * 16 + col16) * 40 + kgrp * 8]);
            f32x4 z = (f32x4){0.f, 0.f, 0.f, 0.f};
            sc[nt] = mfma16(qa, kf, z);
        }
        // ---- softmax per row (row lives in one 16-lane group; 4 rows per group via regs) ----
#pragma unroll
        for (int r = 0; r < 4; ++r) {
            float m = fmaxf(fmaxf(sc[0][r], sc[1][r]), fmaxf(sc[2][r], sc[3][r]));
#pragma unroll
            for (int d = 1; d < 16; d <<= 1) m = fmaxf(m, __shfl_xor(m, d, 16));
            float p[4]; float sum = 0.f;
#pragma unroll
            for (int nt = 0; nt < 4; ++nt) { p[nt] = __expf(sc[nt][r] - m); sum += p[nt]; }
#pragma unroll
            for (int d = 1; d < 16; d <<= 1) sum += __shfl_xor(sum, d, 16);
            float inv = 1.0f / sum;
            int prow = wv * 16 + kgrp * 4 + r;
#pragma unroll
            for (int nt = 0; nt < 4; ++nt) ps[prow * 72 + nt * 16 + col16] = f2bf(p[nt] * inv);
        }
        // ---- PV: A=P (wave-local rows -> no barrier), B=V^T from v_t ----
        f32x4 o[2];
        o[0] = (f32x4){0.f, 0.f, 0.f, 0.f};
        o[1] = (f32x4){0.f, 0.f, 0.f, 0.f};
#pragma unroll
        for (int kt = 0; kt < 2; ++kt) {
            bf16x8 pa = *reinterpret_cast<const bf16x8*>(&ps[(wv * 16 + col16) * 72 + kt * 32 + kgrp * 8]);
#pragma unroll
            for (int nt = 0; nt < 2; ++nt) {
                bf16x8 vb = *reinterpret_cast<const bf16x8*>(&v_t[(nt * 16 + col16) * 72 + kt * 32 + kgrp * 8]);
                o[nt] = mfma16(pa, vb, o[nt]);
            }
        }
        // ---- stash y_head into ps (wave-local rows, cols 0..31), bf16 ----
#pragma unroll
        for (int nt = 0; nt < 2; ++nt)
#pragma unroll
            for (int r = 0; r < 4; ++r)
                ps[(wv * 16 + kgrp * 4 + r) * 72 + nt * 16 + col16] = f2bf(o[nt][r]);
        __syncthreads();   // SYNC2: y_head visible; prior-phase LDS free to overwrite next iter

        // ---- proj rank-32 update: pacc += y_head[64x32] @ wp[h*32..+32, 384] ----
#pragma unroll
        for (int mt = 0; mt < 2; ++mt) {
            bf16x8 ya = *reinterpret_cast<const bf16x8*>(&ps[(wm * 32 + mt * 16 + col16) * 72 + kgrp * 8]);
#pragma unroll
            for (int nt = 0; nt < 12; ++nt) {
                bf16x8 wb = *reinterpret_cast<const bf16x8*>(
                    &wp_t[(wn * 192 + nt * 16 + col16) * 384 + h * 32 + kgrp * 8]);
                pacc[mt][nt] = mfma16(ya, wb, pacc[mt][nt]);
            }
        }
        // next head's q_s/k_s/v_t writes happen before its SYNC1; ps rewrite happens after
        // its SYNC1 — both ordered w.r.t. our proj reads (which precede next SYNC1). safe.
    }

    // ---- epilogue: bias + window_reverse scatter ----
#pragma unroll
    for (int nt = 0; nt < 12; ++nt) {
        int c = wn * 192 + nt * 16 + col16;
        float bias = b_proj[c];
#pragma unroll
        for (int mt = 0; mt < 2; ++mt) {
#pragma unroll
            for (int r = 0; r < 4; ++r) {
                int token = (wm * 2 + mt) * 16 + kgrp * 4 + r;
                int hh = whr * 8 + (token >> 3);
                int ww2 = wwc * 8 + (token & 7);
                out[(((b * 64) + hh) * 64 + ww2) * 384 + c] = pacc[mt][nt][r] + bias;
            }
        }
    }
}

extern "C" void kernel_launch(void* const* d_in, const int* in_sizes, int n_in,
                              void* d_out, int out_size, void* d_ws, size_t ws_size,
                              hipStream_t stream) {
    const float* x     = (const float*)d_in[0];
    const float* wqkv  = (const float*)d_in[1];
    const float* wproj = (const float*)d_in[2];
    const float* bproj = (const float*)d_in[3];

    short* wq_t = (short*)d_ws;            // 1152*384 bf16 = 884,736 B
    short* wp_t = wq_t + 1152 * 384;       //  384*384 bf16 = 294,912 B (total 1.13 MB of ws)

    prep_weights<<<2304, 256, 0, stream>>>(wqkv, wproj, wq_t, wp_t);
    win_attn<<<2048, 256, 0, stream>>>(x, wq_t, wp_t, bproj, (float*)d_out);
}

// Round 2
// 441.500 us; speedup vs baseline: 1.5414x; 1.5414x over previous
//
#include <hip/hip_runtime.h>

// B=32, H=W=64, C=384, ws=8, heads=12, hd=32; windows=2048, N=64 tokens.
// Block = 2 windows, 512 threads (8 waves). Per-head QKV weights staged in LDS
// via global_load_lds from a pre-swizzled image in d_ws; x lives in registers.

typedef __attribute__((ext_vector_type(8))) short bf16x8;   // 8 bf16 (4 VGPR) MFMA A/B frag
typedef __attribute__((ext_vector_type(4))) float f32x4;    // MFMA C/D frag
typedef __attribute__((ext_vector_type(4))) short short4_t;

__device__ __forceinline__ short f2bf(float f) {
    union { float f; unsigned u; } v; v.f = f;
    unsigned r = v.u + 0x7fffu + ((v.u >> 16) & 1u);   // RNE
    return (short)(r >> 16);
}

__device__ __forceinline__ f32x4 mfma16(bf16x8 a, bf16x8 b, f32x4 c) {
    return __builtin_amdgcn_mfma_f32_16x16x32_bf16(a, b, c, 0, 0, 0);
}

__device__ __forceinline__ short4_t pack4(f32x4 v) {
    short4_t s;
    s.x = f2bf(v[0]); s.y = f2bf(v[1]); s.z = f2bf(v[2]); s.w = f2bf(v[3]);
    return s;
}

__device__ __forceinline__ void gload_lds16(const void* g, void* l) {
    __builtin_amdgcn_global_load_lds(
        (const __attribute__((address_space(1))) unsigned int*)g,
        (__attribute__((address_space(3))) unsigned int*)l, 16, 0, 0);
}

// ---- prep: build swizzled per-head QKV weight LDS-image + transposed proj weights ----
// wq_sw[h][o]: LDS byte L=2*o holds W_t[row][k] with row=L/768, k=((L%768)^((row&7)<<4))/2.
// row 0..31 = Q dims, 32..63 = K, 64..95 = V (head h). W_t[row][k] = wqkv[k][col(row,h)].
__global__ void prep_weights(const float* __restrict__ wqkv, const float* __restrict__ wproj,
                             short* __restrict__ wq_sw, short* __restrict__ wp_t) {
    const int QKV_ELEMS = 12 * 96 * 384;
    int i = blockIdx.x * 256 + threadIdx.x;
    if (i < QKV_ELEMS) {
        int h = i / (96 * 384);
        int o = i % (96 * 384);
        int row = o / 384;
        int kb = ((o % 384) * 2) ^ ((row & 7) << 4);
        int k = kb >> 1;
        int col = (row >> 5) * 384 + h * 32 + (row & 31);
        wq_sw[i] = f2bf(wqkv[k * 1152 + col]);
    } else if (i < QKV_ELEMS + 384 * 384) {
        int j = i - QKV_ELEMS;
        int n = j / 384, k = j % 384;
        wp_t[j] = f2bf(wproj[k * 384 + n]);
    }
}

__global__ __launch_bounds__(512, 2)
void win_attn(const float* __restrict__ x, const short* __restrict__ wq_sw,
              const short* __restrict__ wp_t, const float* __restrict__ b_proj,
              float* __restrict__ out) {
    __shared__ short Wl[96 * 384];       // 73,728 B swizzled per-head QKV weights
    __shared__ short q_s[2][64 * 40];    // Q [tok][dim], pre-scaled        10,240 B
    __shared__ short k_s[2][64 * 40];    // K [tok][dim]                    10,240 B
    __shared__ short v_t[2][32 * 72];    // V^T [dim][tok]                   9,216 B
    __shared__ short ps[2][64 * 72];     // P [q][k]; then y [tok][dim]     18,432 B
    // total 121,856 B -> 1 block/CU, 8 waves (2/SIMD)

    const int tid   = threadIdx.x;
    const int lane  = tid & 63;
    const int wv    = tid >> 6;      // 0..7
    const int col16 = lane & 15;
    const int kgrp  = lane >> 4;     // 0..3
    const int wwin  = wv >> 2;       // window within block
    const int q4    = wv & 3;        // quad within window (owns token-tile q4)
    const int wm    = q4 >> 1, wn = q4 & 1;   // proj-phase 2x2 split

    const int win = blockIdx.x * 2 + wwin;
    const int b = win >> 6, wi = win & 63, whr = wi >> 3, wwc = wi & 7;
    const float* xbase = x + (((b * 64) + whr * 8) * 64 + wwc * 8) * 384;

    // ---- issue DMA of head-0 QKV weights (async; drained by first barrier) ----
    {
        const short* src = wq_sw;   // head 0
#pragma unroll
        for (int i = 0; i < 9; ++i) {
            int chunk = wv * 9 + i;                       // 72 chunks of 1 KiB
            gload_lds16(src + chunk * 512 + lane * 8, &Wl[chunk * 512]);
        }
    }

    // ---- x token-tile -> registers (48 VGPR), overlaps with W DMA ----
    bf16x8 xf[12];
    {
        int t = q4 * 16 + col16;
        const float* xr = xbase + ((t >> 3) * 64 + (t & 7)) * 384;
#pragma unroll
        for (int kk = 0; kk < 12; ++kk) {
            const float* p0 = xr + kk * 32 + kgrp * 8;
            float4 a = *reinterpret_cast<const float4*>(p0);
            float4 c = *reinterpret_cast<const float4*>(p0 + 4);
            bf16x8 f;
            f[0] = f2bf(a.x); f[1] = f2bf(a.y); f[2] = f2bf(a.z); f[3] = f2bf(a.w);
            f[4] = f2bf(c.x); f[5] = f2bf(c.y); f[6] = f2bf(c.z); f[7] = f2bf(c.w);
            xf[kk] = f;
        }
    }

    const float scale = 0.17677669529663687f;   // 32^-0.5 folded into Q

    f32x4 pacc[2][12];                           // proj accumulators (96 VGPR)
#pragma unroll
    for (int i = 0; i < 2; ++i)
#pragma unroll
        for (int j = 0; j < 12; ++j) pacc[i][j] = (f32x4){0.f, 0.f, 0.f, 0.f};

    for (int h = 0; h < 12; ++h) {
        __syncthreads();   // B0: W(h) DMA drained + qkv bufs free (prev proj done)

        // ---- QKV: Q/K via mfma(W,x) -> D[dim][tok]; V via mfma(x,W) -> D[tok][dim] ----
        f32x4 acc[6];
#pragma unroll
        for (int i = 0; i < 6; ++i) acc[i] = (f32x4){0.f, 0.f, 0.f, 0.f};
#pragma unroll
        for (int kk = 0; kk < 12; ++kk) {
            const int kbyte = (kk * 32 + kgrp * 8) * 2;
#pragma unroll
            for (int rd = 0; rd < 6; ++rd) {    // 0,1=Q d0,d1; 2,3=K; 4,5=V
                const int row = (rd >> 1) * 32 + (rd & 1) * 16 + col16;
                const bf16x8 wf = *reinterpret_cast<const bf16x8*>(
                    (const char*)Wl + row * 768 + (kbyte ^ ((row & 7) << 4)));
                if ((rd >> 1) < 2) acc[rd] = mfma16(wf, xf[kk], acc[rd]);
                else               acc[rd] = mfma16(xf[kk], wf, acc[rd]);
            }
        }
        // Q/K scatter: lane holds D[dim=kgrp*4+r][tok=col16] -> 4 consecutive dims = b64
#pragma unroll
        for (int rd = 0; rd < 4; ++rd) {
            f32x4 v = acc[rd];
            if (rd < 2) { v[0] *= scale; v[1] *= scale; v[2] *= scale; v[3] *= scale; }
            short* dst = (rd < 2) ? q_s[wwin] : k_s[wwin];
            *reinterpret_cast<short4_t*>(
                &dst[(q4 * 16 + col16) * 40 + (rd & 1) * 16 + kgrp * 4]) = pack4(v);
        }
        // V scatter: lane holds D[tok=kgrp*4+r][dim=d*16+col16] -> v_t[dim][tok] b64
#pragma unroll
        for (int d = 0; d < 2; ++d)
            *reinterpret_cast<short4_t*>(
                &v_t[wwin][(d * 16 + col16) * 72 + q4 * 16 + kgrp * 4]) = pack4(acc[4 + d]);

        __syncthreads();   // B1: qkv visible; Wl fully read -> safe to DMA next head

        if (h < 11) {      // prefetch W(h+1); hides under scores/softmax/PV
            const short* src = wq_sw + (h + 1) * (96 * 384);
#pragma unroll
            for (int i = 0; i < 9; ++i) {
                int chunk = wv * 9 + i;
                gload_lds16(src + chunk * 512 + lane * 8, &Wl[chunk * 512]);
            }
        }

        // ---- scores: wave owns q-rows q4*16..+15; D[q][k], K=32 in one MFMA ----
        bf16x8 qa = *reinterpret_cast<const bf16x8*>(
            &q_s[wwin][(q4 * 16 + col16) * 40 + kgrp * 8]);
        f32x4 sc[4];
#pragma unroll
        for (int nt = 0; nt < 4; ++nt) {
            bf16x8 kf = *reinterpret_cast<const bf16x8*>(
                &k_s[wwin][(nt * 16 + col16) * 40 + kgrp * 8]);
            f32x4 z = (f32x4){0.f, 0.f, 0.f, 0.f};
            sc[nt] = mfma16(qa, kf, z);
        }
        // ---- softmax: 4 independent row-chains, step-outer so chains interleave ----
        float mx[4], sm[4], p[4][4];
#pragma unroll
        for (int r = 0; r < 4; ++r)
            mx[r] = fmaxf(fmaxf(sc[0][r], sc[1][r]), fmaxf(sc[2][r], sc[3][r]));
#pragma unroll
        for (int d = 1; d < 16; d <<= 1)
#pragma unroll
            for (int r = 0; r < 4; ++r) mx[r] = fmaxf(mx[r], __shfl_xor(mx[r], d, 16));
#pragma unroll
        for (int r = 0; r < 4; ++r) {
            sm[r] = 0.f;
#pragma unroll
            for (int nt = 0; nt < 4; ++nt) { p[nt][r] = __expf(sc[nt][r] - mx[r]); sm[r] += p[nt][r]; }
        }
#pragma unroll
        for (int d = 1; d < 16; d <<= 1)
#pragma unroll
            for (int r = 0; r < 4; ++r) sm[r] += __shfl_xor(sm[r], d, 16);
#pragma unroll
        for (int r = 0; r < 4; ++r) {
            float inv = 1.0f / sm[r];
            int prow = q4 * 16 + kgrp * 4 + r;
#pragma unroll
            for (int nt = 0; nt < 4; ++nt)
                ps[wwin][prow * 72 + nt * 16 + col16] = f2bf(p[nt][r] * inv);
        }
        // ---- PV via mfma(V^T, P) -> D[dim][q]; wave-local ps rows, no barrier ----
        f32x4 o2[2];
        o2[0] = (f32x4){0.f, 0.f, 0.f, 0.f};
        o2[1] = (f32x4){0.f, 0.f, 0.f, 0.f};
#pragma unroll
        for (int kt = 0; kt < 2; ++kt) {
            bf16x8 pb = *reinterpret_cast<const bf16x8*>(
                &ps[wwin][(q4 * 16 + col16) * 72 + kt * 32 + kgrp * 8]);
#pragma unroll
            for (int d = 0; d < 2; ++d) {
                bf16x8 va = *reinterpret_cast<const bf16x8*>(
                    &v_t[wwin][(d * 16 + col16) * 72 + kt * 32 + kgrp * 8]);
                o2[d] = mfma16(va, pb, o2[d]);
            }
        }
        // y stash: lane holds D[dim=kgrp*4+r][tok=col16] -> ps[tok][dim] b64
#pragma unroll
        for (int d = 0; d < 2; ++d)
            *reinterpret_cast<short4_t*>(
                &ps[wwin][(q4 * 16 + col16) * 72 + d * 16 + kgrp * 4]) = pack4(o2[d]);

        __syncthreads();   // B2: y visible within window

        // ---- proj rank-32 update: pacc += y[64x32] @ wp[h*32..+32][384] ----
#pragma unroll
        for (int mt = 0; mt < 2; ++mt) {
            bf16x8 ya = *reinterpret_cast<const bf16x8*>(
                &ps[wwin][(wm * 32 + mt * 16 + col16) * 72 + kgrp * 8]);
#pragma unroll
            for (int nt = 0; nt < 12; ++nt) {
                bf16x8 wb = *reinterpret_cast<const bf16x8*>(
                    &wp_t[(wn * 192 + nt * 16 + col16) * 384 + h * 32 + kgrp * 8]);
                pacc[mt][nt] = mfma16(ya, wb, pacc[mt][nt]);
            }
        }
    }

    // ---- epilogue: bias + window_reverse scatter (per window) ----
#pragma unroll
    for (int nt = 0; nt < 12; ++nt) {
        int c = wn * 192 + nt * 16 + col16;
        float bias = b_proj[c];
#pragma unroll
        for (int mt = 0; mt < 2; ++mt) {
#pragma unroll
            for (int r = 0; r < 4; ++r) {
                int token = wm * 32 + mt * 16 + kgrp * 4 + r;
                int hh = whr * 8 + (token >> 3);
                int ww2 = wwc * 8 + (token & 7);
                out[(((b * 64) + hh) * 64 + ww2) * 384 + c] = pacc[mt][nt][r] + bias;
            }
        }
    }
}

extern "C" void kernel_launch(void* const* d_in, const int* in_sizes, int n_in,
                              void* d_out, int out_size, void* d_ws, size_t ws_size,
                              hipStream_t stream) {
    const float* x     = (const float*)d_in[0];
    const float* wqkv  = (const float*)d_in[1];
    const float* wproj = (const float*)d_in[2];
    const float* bproj = (const float*)d_in[3];

    short* wq_sw = (short*)d_ws;                 // 12*96*384 bf16 = 884,736 B (swizzled)
    short* wp_t  = wq_sw + 12 * 96 * 384;        // 384*384 bf16 = 294,912 B

    prep_weights<<<2304, 256, 0, stream>>>(wqkv, wproj, wq_sw, wp_t);
    win_attn<<<1024, 512, 0, stream>>>(x, wq_sw, wp_t, bproj, (float*)d_out);
}

// Round 4
// 390.729 us; speedup vs baseline: 1.7416x; 1.1299x over previous
//
#include <hip/hip_runtime.h>

// B=32, H=W=64, C=384, ws=8, heads=12, hd=32; windows=2048, N=64 tokens.
// Path 1 (needs ~102MB d_ws): prep -> qkv_attn (4 win/block, 16 waves, y->ws swizzled)
//                                  -> proj_gemm (128x128 tiles, window_reverse epilogue)
// Path 2 (fallback, small ws):  prep -> win_attn_fused (round-2 kernel)

typedef __attribute__((ext_vector_type(8))) short bf16x8;   // 8 bf16 (4 VGPR) MFMA A/B frag
typedef __attribute__((ext_vector_type(4))) float f32x4;    // MFMA C/D frag
typedef __attribute__((ext_vector_type(4))) short short4_t;

__device__ __forceinline__ short f2bf(float f) {
    union { float f; unsigned u; } v; v.f = f;
    unsigned r = v.u + 0x7fffu + ((v.u >> 16) & 1u);   // RNE
    return (short)(r >> 16);
}

__device__ __forceinline__ unsigned pk2(float a, float b) {   // 2xbf16 dword (a=low)
    return ((unsigned)(unsigned short)f2bf(b) << 16) | (unsigned short)f2bf(a);
}

__device__ __forceinline__ f32x4 mfma16(bf16x8 a, bf16x8 b, f32x4 c) {
    return __builtin_amdgcn_mfma_f32_16x16x32_bf16(a, b, c, 0, 0, 0);
}

__device__ __forceinline__ short4_t pack4(f32x4 v) {
    short4_t s;
    s.x = f2bf(v[0]); s.y = f2bf(v[1]); s.z = f2bf(v[2]); s.w = f2bf(v[3]);
    return s;
}

__device__ __forceinline__ void gload_lds16(const void* g, void* l) {
    __builtin_amdgcn_global_load_lds(
        (const __attribute__((address_space(1))) unsigned int*)g,
        (__attribute__((address_space(3))) unsigned int*)l, 16, 0, 0);
}

// ---- prep: swizzled per-head QKV weights (Q rows pre-scaled) + transposed proj ----
// wq_sw[h][o]: byte L=2*o holds W_t[row][k], row=L/768, k=((L%768)^((row&7)<<4))/2.
// rows 0..31 = Q dims (x scale), 32..63 = K, 64..95 = V. W_t[row][k]=wqkv[k][col(row,h)].
__global__ void prep_weights(const float* __restrict__ wqkv, const float* __restrict__ wproj,
                             short* __restrict__ wq_sw, short* __restrict__ wp_t) {
    const int QKV_ELEMS = 12 * 96 * 384;
    int i = blockIdx.x * 256 + threadIdx.x;
    if (i < QKV_ELEMS) {
        int h = i / (96 * 384);
        int o = i % (96 * 384);
        int row = o / 384;
        int kb = ((o % 384) * 2) ^ ((row & 7) << 4);
        int k = kb >> 1;
        int col = (row >> 5) * 384 + h * 32 + (row & 31);
        float w = wqkv[k * 1152 + col];
        if (row < 32) w *= 0.17677669529663687f;   // 32^-0.5 folded into Q
        wq_sw[i] = f2bf(w);
    } else if (i < QKV_ELEMS + 384 * 384) {
        int j = i - QKV_ELEMS;
        int n = j / 384, k = j % 384;
        wp_t[j] = f2bf(wproj[k * 384 + n]);
    }
}

// ================= Path 1, kernel A: QKV + attention, y -> ws (swizzled) ==========
__global__ __launch_bounds__(1024)
void qkv_attn(const float* __restrict__ x, const short* __restrict__ wq_sw,
              short* __restrict__ y_sw) {
    __shared__ short Wl[96 * 384];       // 73,728 B per-head swizzled QKV weights
    __shared__ short k_s[4][64 * 40];    // K [tok][dim]                20,480 B
    __shared__ short v_t[4][32 * 72];    // V^T [dim][tok]              18,432 B
    __shared__ short ps[4][64 * 72];     // P [q][k] (wave-local rows)  36,864 B
    // total 149,504 B -> 1 block/CU, 16 waves = 4/SIMD

    const int tid   = threadIdx.x;
    const int lane  = tid & 63;
    const int wv    = tid >> 6;      // 0..15
    const int col16 = lane & 15;
    const int kgrp  = lane >> 4;     // 0..3
    const int wwin  = wv >> 2;       // window within block 0..3
    const int quad  = wv & 3;        // quad in window (owns token-tile quad)

    const int win = blockIdx.x * 4 + wwin;
    const int b = win >> 6, wi = win & 63, whr = wi >> 3, wwc = wi & 7;
    const float* xbase = x + (((b * 64) + whr * 8) * 64 + wwc * 8) * 384;

    // ---- issue DMA of head-0 weights ----
    for (int i = wv; i < 72; i += 16)
        gload_lds16(wq_sw + i * 512 + lane * 8, &Wl[i * 512]);

    // ---- x token-tile -> registers (48 VGPR) ----
    bf16x8 xf[12];
    {
        int t = quad * 16 + col16;
        const float* xr = xbase + ((t >> 3) * 64 + (t & 7)) * 384;
#pragma unroll
        for (int kk = 0; kk < 12; ++kk) {
            const float* p0 = xr + kk * 32 + kgrp * 8;
            float4 a = *reinterpret_cast<const float4*>(p0);
            float4 c = *reinterpret_cast<const float4*>(p0 + 4);
            bf16x8 f;
            f[0] = f2bf(a.x); f[1] = f2bf(a.y); f[2] = f2bf(a.z); f[3] = f2bf(a.w);
            f[4] = f2bf(c.x); f[5] = f2bf(c.y); f[6] = f2bf(c.z); f[7] = f2bf(c.w);
            xf[kk] = f;
        }
    }

    // y addressing: token g, its A-tile row/mtile (proj GEMM image)
    const int g = win * 64 + quad * 16 + col16;
    const int mtile = g >> 7, yrow = g & 127;
    char* ybase = (char*)y_sw + (size_t)mtile * 98304 + (size_t)yrow * 128;

    for (int h = 0; h < 12; ++h) {
        __syncthreads();   // B0: W(h) DMA drained; k_s/v_t free (prev head reads done)

        // ---- QKV: Q/K via mfma(W,x) -> D[dim][tok]; V via mfma(x,W) -> D[tok][dim] ----
        f32x4 acc[6];
#pragma unroll
        for (int i = 0; i < 6; ++i) acc[i] = (f32x4){0.f, 0.f, 0.f, 0.f};
#pragma unroll
        for (int kk = 0; kk < 12; ++kk) {
            const int kbyte = (kk * 32 + kgrp * 8) * 2;
#pragma unroll
            for (int rd = 0; rd < 6; ++rd) {
                const int row = (rd >> 1) * 32 + (rd & 1) * 16 + col16;
                const bf16x8 wf = *reinterpret_cast<const bf16x8*>(
                    (const char*)Wl + row * 768 + (kbyte ^ ((row & 7) << 4)));
                if (rd < 4) acc[rd] = mfma16(wf, xf[kk], acc[rd]);
                else        acc[rd] = mfma16(xf[kk], wf, acc[rd]);
            }
        }
        // ---- Q relayout D[dim][tok] -> A-frag[tok][dim], in-register ----
        // src lane (c,g): acc[0][r]=Q[4g+r][c] (dims 0..15), acc[1][r]=Q[16+4g+r][c].
        // pack per-lane: A0=(Q[4g],Q[4g+1]) A1=(Q[4g+2],Q[4g+3]) (bf16 pairs 2g,2g+1)
        //                B0,B1 = same from acc[1] (pairs 8+2g, 8+2g+1).
        // dest (c',g') needs pairs 4g'..4g'+3 = {A|B}-pairs of src lanes (c',2(g'&1)),(c',2(g'&1)+1);
        // A-side if g'<2 else B-side (select AFTER shuffle, by dest's kgrp).
        bf16x8 qa;
        {
            unsigned A0 = pk2(acc[0][0], acc[0][1]);
            unsigned A1 = pk2(acc[0][2], acc[0][3]);
            unsigned B0 = pk2(acc[1][0], acc[1][1]);
            unsigned B1 = pk2(acc[1][2], acc[1][3]);
            int s0 = ((kgrp & 1) * 2) * 16 + col16;
            int a0 = __shfl((int)A0, s0, 64),      a1 = __shfl((int)A1, s0, 64);
            int a2 = __shfl((int)A0, s0 + 16, 64), a3 = __shfl((int)A1, s0 + 16, 64);
            int b0 = __shfl((int)B0, s0, 64),      b1 = __shfl((int)B1, s0, 64);
            int b2 = __shfl((int)B0, s0 + 16, 64), b3 = __shfl((int)B1, s0 + 16, 64);
            union { int i[4]; bf16x8 v; } qu;
            const bool loHalf = (kgrp < 2);
            qu.i[0] = loHalf ? a0 : b0;
            qu.i[1] = loHalf ? a1 : b1;
            qu.i[2] = loHalf ? a2 : b2;
            qu.i[3] = loHalf ? a3 : b3;
            qa = qu.v;
        }
        // ---- K scatter (b64): k_s[tok][dim] ----
#pragma unroll
        for (int rd = 2; rd < 4; ++rd)
            *reinterpret_cast<short4_t*>(
                &k_s[wwin][(quad * 16 + col16) * 40 + (rd & 1) * 16 + kgrp * 4]) = pack4(acc[rd]);
        // ---- V scatter (b64): v_t[dim][tok] ----
#pragma unroll
        for (int d = 0; d < 2; ++d)
            *reinterpret_cast<short4_t*>(
                &v_t[wwin][(d * 16 + col16) * 72 + quad * 16 + kgrp * 4]) = pack4(acc[4 + d]);

        __syncthreads();   // B1: K/V visible; Wl fully read -> safe to DMA next head

        if (h < 11) {
            const short* src = wq_sw + (h + 1) * (96 * 384);
            for (int i = wv; i < 72; i += 16)
                gload_lds16(src + i * 512 + lane * 8, &Wl[i * 512]);
        }

        // ---- scores: wave owns q-rows quad*16..+15 ----
        f32x4 sc[4];
#pragma unroll
        for (int nt = 0; nt < 4; ++nt) {
            bf16x8 kf = *reinterpret_cast<const bf16x8*>(
                &k_s[wwin][(nt * 16 + col16) * 40 + kgrp * 8]);
            f32x4 z = (f32x4){0.f, 0.f, 0.f, 0.f};
            sc[nt] = mfma16(qa, kf, z);
        }
        // ---- softmax (4 independent row-chains) ----
        float mx[4], sm[4];
#pragma unroll
        for (int r = 0; r < 4; ++r)
            mx[r] = fmaxf(fmaxf(sc[0][r], sc[1][r]), fmaxf(sc[2][r], sc[3][r]));
#pragma unroll
        for (int d = 1; d < 16; d <<= 1)
#pragma unroll
            for (int r = 0; r < 4; ++r) mx[r] = fmaxf(mx[r], __shfl_xor(mx[r], d, 16));
#pragma unroll
        for (int r = 0; r < 4; ++r) {
            sm[r] = 0.f;
#pragma unroll
            for (int nt = 0; nt < 4; ++nt) {
                sc[nt][r] = __expf(sc[nt][r] - mx[r]); sm[r] += sc[nt][r];
            }
        }
#pragma unroll
        for (int d = 1; d < 16; d <<= 1)
#pragma unroll
            for (int r = 0; r < 4; ++r) sm[r] += __shfl_xor(sm[r], d, 16);
#pragma unroll
        for (int r = 0; r < 4; ++r) {
            float inv = 1.0f / sm[r];
            int prow = quad * 16 + kgrp * 4 + r;
#pragma unroll
            for (int nt = 0; nt < 4; ++nt)
                ps[wwin][prow * 72 + nt * 16 + col16] = f2bf(sc[nt][r] * inv);
        }
        // ---- PV via mfma(V^T, P) -> D[dim][q]; wave-local ps rows ----
        f32x4 o2[2];
        o2[0] = (f32x4){0.f, 0.f, 0.f, 0.f};
        o2[1] = (f32x4){0.f, 0.f, 0.f, 0.f};
#pragma unroll
        for (int kt = 0; kt < 2; ++kt) {
            bf16x8 pb = *reinterpret_cast<const bf16x8*>(
                &ps[wwin][(quad * 16 + col16) * 72 + kt * 32 + kgrp * 8]);
#pragma unroll
            for (int d = 0; d < 2; ++d) {
                bf16x8 va = *reinterpret_cast<const bf16x8*>(
                    &v_t[wwin][(d * 16 + col16) * 72 + kt * 32 + kgrp * 8]);
                o2[d] = mfma16(va, pb, o2[d]);
            }
        }
        // ---- y write (swizzled proj-A image): token=col16-row, dims kgrp*4..+3 ----
#pragma unroll
        for (int d = 0; d < 2; ++d) {
            int c0 = h * 32 + d * 16 + kgrp * 4;
            int kchunk = c0 >> 6;
            int koff = (2 * (c0 & 63)) ^ ((yrow & 7) << 4);
            *reinterpret_cast<short4_t*>(ybase + kchunk * 16384 + koff) = pack4(o2[d]);
        }
    }
}

// ================= Path 1, kernel B: out = y @ wp + bias, window_reverse ==========
__global__ __launch_bounds__(256)
void proj_gemm(const short* __restrict__ y_sw, const short* __restrict__ wp_t,
               const float* __restrict__ b_proj, float* __restrict__ out) {
    __shared__ short At[2][128 * 64];   // 2 x 16 KiB swizzled A tiles

    const int tid = threadIdx.x, lane = tid & 63, wv = tid >> 6;
    const int col16 = lane & 15, kgrp = lane >> 4;
    const int wm = wv >> 1, wn = wv & 1;
    const int mtile = blockIdx.x;       // 0..1023
    const int nblk  = blockIdx.y;       // 0..2

    const short* asrc = y_sw + (size_t)mtile * 6 * 128 * 64;

    // prologue: stage kchunk 0
    for (int i = wv; i < 16; i += 4)
        gload_lds16(asrc + i * 512 + lane * 8, &At[0][i * 512]);

    const short* bptr[4];
#pragma unroll
    for (int nt = 0; nt < 4; ++nt)
        bptr[nt] = wp_t + (size_t)(nblk * 128 + wn * 64 + nt * 16 + col16) * 384;

    f32x4 acc[4][4];
#pragma unroll
    for (int i = 0; i < 4; ++i)
#pragma unroll
        for (int j = 0; j < 4; ++j) acc[i][j] = (f32x4){0.f, 0.f, 0.f, 0.f};

    int cur = 0;
    for (int ks = 0; ks < 6; ++ks) {
        __syncthreads();               // buf[cur] ready (vmcnt drained by barrier)
        if (ks < 5) {
            const short* src = asrc + (ks + 1) * (128 * 64);
            for (int i = wv; i < 16; i += 4)
                gload_lds16(src + i * 512 + lane * 8, &At[cur ^ 1][i * 512]);
        }
#pragma unroll
        for (int kk = 0; kk < 2; ++kk) {
            const int kbyte = kk * 64 + kgrp * 16;
            bf16x8 af[4];
#pragma unroll
            for (int mt = 0; mt < 4; ++mt) {
                const int r = wm * 64 + mt * 16 + col16;
                af[mt] = *reinterpret_cast<const bf16x8*>(
                    (const char*)At[cur] + r * 128 + (kbyte ^ ((r & 7) << 4)));
            }
#pragma unroll
            for (int nt = 0; nt < 4; ++nt) {
                bf16x8 bf = *reinterpret_cast<const bf16x8*>(bptr[nt] + ks * 64 + kk * 32 + kgrp * 8);
#pragma unroll
                for (int mt = 0; mt < 4; ++mt)
                    acc[mt][nt] = mfma16(af[mt], bf, acc[mt][nt]);
            }
        }
        cur ^= 1;
    }

    // epilogue: bias + window_reverse scatter
#pragma unroll
    for (int nt = 0; nt < 4; ++nt) {
        int c = nblk * 128 + wn * 64 + nt * 16 + col16;
        float bias = b_proj[c];
#pragma unroll
        for (int mt = 0; mt < 4; ++mt) {
#pragma unroll
            for (int r = 0; r < 4; ++r) {
                int gg = mtile * 128 + wm * 64 + mt * 16 + kgrp * 4 + r;
                int win = gg >> 6, t = gg & 63;
                int b = win >> 6, whr = (win >> 3) & 7, wwc = win & 7;
                int orow = (b * 64 + whr * 8 + (t >> 3)) * 64 + wwc * 8 + (t & 7);
                out[(size_t)orow * 384 + c] = acc[mt][nt][r] + bias;
            }
        }
    }
}

// ================= Path 2 fallback: round-2 fused kernel (scale now in prep) ======
__global__ __launch_bounds__(512, 2)
void win_attn_fused(const float* __restrict__ x, const short* __restrict__ wq_sw,
                    const short* __restrict__ wp_t, const float* __restrict__ b_proj,
                    float* __restrict__ out) {
    __shared__ short Wl[96 * 384];
    __shared__ short q_s[2][64 * 40];
    __shared__ short k_s[2][64 * 40];
    __shared__ short v_t[2][32 * 72];
    __shared__ short ps[2][64 * 72];

    const int tid   = threadIdx.x;
    const int lane  = tid & 63;
    const int wv    = tid >> 6;
    const int col16 = lane & 15;
    const int kgrp  = lane >> 4;
    const int wwin  = wv >> 2;
    const int q4    = wv & 3;
    const int wm    = q4 >> 1, wn = q4 & 1;

    const int win = blockIdx.x * 2 + wwin;
    const int b = win >> 6, wi = win & 63, whr = wi >> 3, wwc = wi & 7;
    const float* xbase = x + (((b * 64) + whr * 8) * 64 + wwc * 8) * 384;

    for (int i = 0; i < 9; ++i) {
        int chunk = wv * 9 + i;
        gload_lds16(wq_sw + chunk * 512 + lane * 8, &Wl[chunk * 512]);
    }
    bf16x8 xf[12];
    {
        int t = q4 * 16 + col16;
        const float* xr = xbase + ((t >> 3) * 64 + (t & 7)) * 384;
#pragma unroll
        for (int kk = 0; kk < 12; ++kk) {
            const float* p0 = xr + kk * 32 + kgrp * 8;
            float4 a = *reinterpret_cast<const float4*>(p0);
            float4 c = *reinterpret_cast<const float4*>(p0 + 4);
            bf16x8 f;
            f[0] = f2bf(a.x); f[1] = f2bf(a.y); f[2] = f2bf(a.z); f[3] = f2bf(a.w);
            f[4] = f2bf(c.x); f[5] = f2bf(c.y); f[6] = f2bf(c.z); f[7] = f2bf(c.w);
            xf[kk] = f;
        }
    }
    f32x4 pacc[2][12];
#pragma unroll
    for (int i = 0; i < 2; ++i)
#pragma unroll
        for (int j = 0; j < 12; ++j) pacc[i][j] = (f32x4){0.f, 0.f, 0.f, 0.f};

    for (int h = 0; h < 12; ++h) {
        __syncthreads();
        f32x4 acc[6];
#pragma unroll
        for (int i = 0; i < 6; ++i) acc[i] = (f32x4){0.f, 0.f, 0.f, 0.f};
#pragma unroll
        for (int kk = 0; kk < 12; ++kk) {
            const int kbyte = (kk * 32 + kgrp * 8) * 2;
#pragma unroll
            for (int rd = 0; rd < 6; ++rd) {
                const int row = (rd >> 1) * 32 + (rd & 1) * 16 + col16;
                const bf16x8 wf = *reinterpret_cast<const bf16x8*>(
                    (const char*)Wl + row * 768 + (kbyte ^ ((row & 7) << 4)));
                if (rd < 4) acc[rd] = mfma16(wf, xf[kk], acc[rd]);
                else        acc[rd] = mfma16(xf[kk], wf, acc[rd]);
            }
        }
#pragma unroll
        for (int rd = 0; rd < 4; ++rd) {
            short* dst = (rd < 2) ? q_s[wwin] : k_s[wwin];
            *reinterpret_cast<short4_t*>(
                &dst[(q4 * 16 + col16) * 40 + (rd & 1) * 16 + kgrp * 4]) = pack4(acc[rd]);
        }
#pragma unroll
        for (int d = 0; d < 2; ++d)
            *reinterpret_cast<short4_t*>(
                &v_t[wwin][(d * 16 + col16) * 72 + q4 * 16 + kgrp * 4]) = pack4(acc[4 + d]);

        __syncthreads();
        if (h < 11) {
            const short* src = wq_sw + (h + 1) * (96 * 384);
            for (int i = 0; i < 9; ++i) {
                int chunk = wv * 9 + i;
                gload_lds16(src + chunk * 512 + lane * 8, &Wl[chunk * 512]);
            }
        }
        bf16x8 qa = *reinterpret_cast<const bf16x8*>(
            &q_s[wwin][(q4 * 16 + col16) * 40 + kgrp * 8]);
        f32x4 sc[4];
#pragma unroll
        for (int nt = 0; nt < 4; ++nt) {
            bf16x8 kf = *reinterpret_cast<const bf16x8*>(
                &k_s[wwin][(nt * 16 + col16) * 40 + kgrp * 8]);
            f32x4 z = (f32x4){0.f, 0.f, 0.f, 0.f};
            sc[nt] = mfma16(qa, kf, z);
        }
        float mx[4], sm[4], p[4][4];
#pragma unroll
        for (int r = 0; r < 4; ++r)
            mx[r] = fmaxf(fmaxf(sc[0][r], sc[1][r]), fmaxf(sc[2][r], sc[3][r]));
#pragma unroll
        for (int d = 1; d < 16; d <<= 1)
#pragma unroll
            for (int r = 0; r < 4; ++r) mx[r] = fmaxf(mx[r], __shfl_xor(mx[r], d, 16));
#pragma unroll
        for (int r = 0; r < 4; ++r) {
            sm[r] = 0.f;
#pragma unroll
            for (int nt = 0; nt < 4; ++nt) { p[nt][r] = __expf(sc[nt][r] - mx[r]); sm[r] += p[nt][r]; }
        }
#pragma unroll
        for (int d = 1; d < 16; d <<= 1)
#pragma unroll
            for (int r = 0; r < 4; ++r) sm[r] += __shfl_xor(sm[r], d, 16);
#pragma unroll
        for (int r = 0; r < 4; ++r) {
            float inv = 1.0f / sm[r];
            int prow = q4 * 16 + kgrp * 4 + r;
#pragma unroll
            for (int nt = 0; nt < 4; ++nt)
                ps[wwin][prow * 72 + nt * 16 + col16] = f2bf(p[nt][r] * inv);
        }
        f32x4 o2[2];
        o2[0] = (f32x4){0.f, 0.f, 0.f, 0.f};
        o2[1] = (f32x4){0.f, 0.f, 0.f, 0.f};
#pragma unroll
        for (int kt = 0; kt < 2; ++kt) {
            bf16x8 pb = *reinterpret_cast<const bf16x8*>(
                &ps[wwin][(q4 * 16 + col16) * 72 + kt * 32 + kgrp * 8]);
#pragma unroll
            for (int d = 0; d < 2; ++d) {
                bf16x8 va = *reinterpret_cast<const bf16x8*>(
                    &v_t[wwin][(d * 16 + col16) * 72 + kt * 32 + kgrp * 8]);
                o2[d] = mfma16(va, pb, o2[d]);
            }
        }
#pragma unroll
        for (int d = 0; d < 2; ++d)
            *reinterpret_cast<short4_t*>(
                &ps[wwin][(q4 * 16 + col16) * 72 + d * 16 + kgrp * 4]) = pack4(o2[d]);
        __syncthreads();
#pragma unroll
        for (int mt = 0; mt < 2; ++mt) {
            bf16x8 ya = *reinterpret_cast<const bf16x8*>(
                &ps[wwin][(wm * 32 + mt * 16 + col16) * 72 + kgrp * 8]);
#pragma unroll
            for (int nt = 0; nt < 12; ++nt) {
                bf16x8 wb = *reinterpret_cast<const bf16x8*>(
                    &wp_t[(wn * 192 + nt * 16 + col16) * 384 + h * 32 + kgrp * 8]);
                pacc[mt][nt] = mfma16(ya, wb, pacc[mt][nt]);
            }
        }
    }
#pragma unroll
    for (int nt = 0; nt < 12; ++nt) {
        int c = wn * 192 + nt * 16 + col16;
        float bias = b_proj[c];
#pragma unroll
        for (int mt = 0; mt < 2; ++mt) {
#pragma unroll
            for (int r = 0; r < 4; ++r) {
                int token = wm * 32 + mt * 16 + kgrp * 4 + r;
                int hh = whr * 8 + (token >> 3);
                int ww2 = wwc * 8 + (token & 7);
                out[(((b * 64) + hh) * 64 + ww2) * 384 + c] = pacc[mt][nt][r] + bias;
            }
        }
    }
}

extern "C" void kernel_launch(void* const* d_in, const int* in_sizes, int n_in,
                              void* d_out, int out_size, void* d_ws, size_t ws_size,
                              hipStream_t stream) {
    const float* x     = (const float*)d_in[0];
    const float* wqkv  = (const float*)d_in[1];
    const float* wproj = (const float*)d_in[2];
    const float* bproj = (const float*)d_in[3];

    short* wq_sw = (short*)d_ws;                  // 884,736 B
    short* wp_t  = wq_sw + 12 * 96 * 384;         // 294,912 B
    short* y_sw  = wp_t + 384 * 384;              // 100,663,296 B (path 1 only)
    const size_t need = (size_t)(12 * 96 * 384 + 384 * 384) * 2 + (size_t)1024 * 6 * 128 * 128;

    prep_weights<<<2304, 256, 0, stream>>>(wqkv, wproj, wq_sw, wp_t);
    if (ws_size >= need) {
        qkv_attn<<<512, 1024, 0, stream>>>(x, wq_sw, y_sw);
        proj_gemm<<<dim3(1024, 3), 256, 0, stream>>>(y_sw, wp_t, bproj, (float*)d_out);
    } else {
        win_attn_fused<<<1024, 512, 0, stream>>>(x, wq_sw, wp_t, bproj, (float*)d_out);
    }
}